// Round 9
// baseline (146.783 us; speedup 1.0000x reference)
//
#include <hip/hip_runtime.h>

// CRF loss on MI355X — pair-packed 4-quad single-phase pipeline (round 9).
// B=512, L=512, T=32, S=34. Output f32[512].
//
// R7/R8 nulls pinned the bottleneck: DS-pipe instruction throughput
// (16x ds_read_b128 + 2 writes/step ~ 190 cy), not VALU issue, not read
// latency margin. Fix: R2's verified 4-chain layout — 4 quads x 16 lanes,
// 2 states/lane (q0=b0 fwd, q1=b0 bwd, q2=b1 fwd, q3=b1 bwd; regions at
// 36-float stride -> 4-bank offset, broadcast reads conflict-free) — so
// ONE 8x ds_read_b128 burst + ONE ds_write_b64 per step serves all 4
// chains (halves DS instructions). R2's 570-cy serial bookkeeping is gone:
// pk_fma accumulators ARE the two states (no horizontal sum), gold path in
// the epilogue, emission ring in the read shadow, 16-step BIAS rescale now
// pure DPP (16-lane groups align with DPP rows — no ds_swizzle).

typedef float f32x2 __attribute__((ext_vector_type(2)));

#define F2   1.4426950408889634f   // log2(e)
#define LN2  0.6931471805599453f
#define BIAS 0.0078125f            // 2^-7, exact
#define BIASCNT 3577               // 7 * 511 applications of biased tc

__device__ __forceinline__ float grpmax16(float x) {
    // max over each 16-lane row: 4 DPP row_ror fmax (verified pattern,
    // rounds 4-8, minus the xor-16 stage — rescale groups are now 16 lanes).
    int t;
    t = __builtin_amdgcn_update_dpp(__float_as_int(x), __float_as_int(x), 0x121, 0xf, 0xf, true);
    x = fmaxf(x, __int_as_float(t));   // row_ror:1
    t = __builtin_amdgcn_update_dpp(__float_as_int(x), __float_as_int(x), 0x122, 0xf, 0xf, true);
    x = fmaxf(x, __int_as_float(t));   // row_ror:2
    t = __builtin_amdgcn_update_dpp(__float_as_int(x), __float_as_int(x), 0x124, 0xf, 0xf, true);
    x = fmaxf(x, __int_as_float(t));   // row_ror:4
    t = __builtin_amdgcn_update_dpp(__float_as_int(x), __float_as_int(x), 0x128, 0xf, 0xf, true);
    x = fmaxf(x, __int_as_float(t));   // row_ror:8 -> per-16 max
    return x;
}

__global__ __launch_bounds__(64, 1) void crf_kernel(
    const float* __restrict__ wtv,    // [512,512,32]
    const float* __restrict__ trans,  // [34,34]
    const int*   __restrict__ rtag,   // [512,512]
    float* __restrict__ out)          // [512]
{
    __shared__ __align__(16) float tlds[1156];  // raw translation (ln domain)
    __shared__ __align__(16) int   ltag[1024];  // gold tags, 2 batches
    __shared__ __align__(16) float alds[144];   // 4 chains * 36 floats

    const int l   = threadIdx.x;
    const int q   = l >> 4;        // chain: 0=b0F, 1=b0B, 2=b1F, 3=b1B
    const int c16 = l & 15;
    const int h   = q & 1;         // 0 = forward, 1 = backward
    const int bp  = q >> 1;        // batch within pair
    const int sA  = 2 * c16;       // lane's two states (0-based tag cols)
    const int sB  = sA + 1;
    const int bbase = blockIdx.x * 2;

    for (int k = l; k < 1156; k += 64) tlds[k] = trans[k];
    {
        const int* rtb = rtag + (size_t)bbase * 512;
        for (int k = l; k < 1024; k += 64) ltag[k] = rtb[k];
    }
    __syncthreads();  // once, before the main loop (graph-safe)

    // exp2-domain transitions (biased), packed per lane-pair of states:
    // fwd: tc2[p] = {T[p+1][sA+1], T[p+1][sB+1]}; bwd: {T[sA+1][p+1], T[sB+1][p+1]}
    f32x2 tc2[32];
    #pragma unroll
    for (int p = 0; p < 32; ++p) {
        float tA = h ? tlds[(sA + 1) * 34 + (p + 1)] : tlds[(p + 1) * 34 + (sA + 1)];
        float tB = h ? tlds[(sB + 1) * 34 + (p + 1)] : tlds[(p + 1) * 34 + (sB + 1)];
        f32x2 v;
        v.x = __builtin_exp2f(F2 * tA) * BIAS;
        v.y = __builtin_exp2f(F2 * tB) * BIAS;
        tc2[p] = v;
    }
    f32x2 ai2 = {0.0f, 0.0f};                       // START term, step 1, fwd only
    if (!h) {
        ai2.x = __builtin_exp2f(F2 * tlds[sA + 1]) * BIAS;
        ai2.y = __builtin_exp2f(F2 * tlds[sB + 1]) * BIAS;
    }

    const float* wbq = wtv + (size_t)(bbase + bp) * (512 * 32);
    const float* wl  = wbq + sA;                    // lane's 2-state column base

    f32x2 st = {1.0f, 1.0f};                        // bwd: b_511
    if (!h) {
        f32x2 v0 = *(const f32x2*)wl;               // row-0 emissions
        st.x = __builtin_exp2f(F2 * v0.x);          // alpha_0
        st.y = __builtin_exp2f(F2 * v0.y);
    }
    int scaleE = 0;

    // emission ring (8 ahead): step i reads row i (fwd) / 512-i (bwd)
    f32x2 vn2[16];
    #pragma unroll
    for (int j = 0; j < 8; ++j)
        vn2[j] = *(const f32x2*)(wl + (h ? (511 - j) * 32 : (1 + j) * 32));
    f32x2 eo_c;
    eo_c.x = __builtin_exp2f(F2 * vn2[0].x);        // emission factor, step 1
    eo_c.y = __builtin_exp2f(F2 * vn2[0].y);

    float*        ach = alds + q * 36;              // region (16B-aligned, +4 banks/quad)
    const float4* a4  = (const float4*)ach;
    f32x2*        wp  = (f32x2*)(ach + sA);

    float4 ra[8];

    for (int t0 = 1; t0 <= 241; t0 += 16) {   // 16 bodies x 16 steps = i = 1..256
        #pragma unroll
        for (int j = 0; j < 16; ++j) {
            const int i = t0 + j;

            // publish: fwd writes alpha_{i-1}, bwd writes g_i = b ⊙ eo_i
            f32x2 wv = h ? st * eo_c : st;
            *wp = wv;
            __builtin_amdgcn_wave_barrier();
            #pragma unroll
            for (int k = 0; k < 8; ++k) ra[k] = a4[k];   // 8x ds_read_b128, all 4 chains
            __builtin_amdgcn_wave_barrier();
            // shadow: emission prefetch (tail rows: fwd <= 264, bwd >= 248,
            // in-bounds, unused past 256) + next-step emission factor
            vn2[(j + 8) & 15] = *(const f32x2*)(wl + (h ? (512 - (i + 8)) * 32
                                                       : (i + 8) * 32));
            f32x2 vcn = vn2[(j + 1) & 15];
            f32x2 eo_n;
            eo_n.x = __builtin_exp2f(F2 * vcn.x);
            eo_n.y = __builtin_exp2f(F2 * vcn.y);

            // matvec: acc (f32x2) accumulates this lane's TWO output states
            f32x2 acc0 = ai2, acc1 = {0.0f, 0.0f};
            f32x2 acc2 = {0.0f, 0.0f}, acc3 = {0.0f, 0.0f};
            ai2.x = 0.0f; ai2.y = 0.0f;
            #pragma unroll
            for (int k = 0; k < 8; ++k) {
                float4 x = ra[k];
                f32x2 x0 = {x.x, x.x}, x1 = {x.y, x.y};
                f32x2 x2 = {x.z, x.z}, x3 = {x.w, x.w};
                acc0 = __builtin_elementwise_fma(x0, tc2[4 * k + 0], acc0);
                acc1 = __builtin_elementwise_fma(x1, tc2[4 * k + 1], acc1);
                acc2 = __builtin_elementwise_fma(x2, tc2[4 * k + 2], acc2);
                acc3 = __builtin_elementwise_fma(x3, tc2[4 * k + 3], acc3);
            }
            f32x2 s2 = (acc0 + acc1) + (acc2 + acc3);
            f32x2 ns = h ? s2 : s2 * eo_c;          // fwd applies emission post-matvec

            bool doUpd = (i != 256) || (h == 0);    // i==256: fwd-only tail step
            st = doUpd ? ns : st;
            eo_c = eo_n;
        }
        // exact power-of-2 rescale, per 16-lane chain (every 16 steps)
        float m = grpmax16(fmaxf(st.x, st.y));
        int e = ((__float_as_int(m) >> 23) & 0xff) - 127;
        float sc = __int_as_float((127 - e) << 23);
        st.x *= sc; st.y *= sc;
        scaleE += e;
    }

    // ---- Z = sum_s af_256[s] * b_256[s] (partner chain = xor 16) ----
    float boA = __shfl_xor(st.x, 16);
    float boB = __shfl_xor(st.y, 16);
    float prod = st.x * boA + st.y * boB;
    prod += __shfl_xor(prod, 1);
    prod += __shfl_xor(prod, 2);
    prod += __shfl_xor(prod, 4);
    prod += __shfl_xor(prod, 8);
    int scTot = scaleE + __shfl_xor(scaleE, 16);
    float total = ((float)(scTot + BIASCNT) + __builtin_log2f(prod)) * LN2;

    // ---- gold-path score epilogue (verified R3-R8): gathers L2/L3-warm ----
    float ps0 = 0.0f, ps1 = 0.0f;
    #pragma unroll
    for (int bb = 0; bb < 2; ++bb) {
        const float* w  = wtv + (size_t)(bbase + bb) * (512 * 32);
        const int*   tg = ltag + (bb << 9);
        int   tcur[8];
        float em[8];
        #pragma unroll
        for (int k = 0; k < 8; ++k) tcur[k] = tg[l + 64 * k];
        #pragma unroll
        for (int k = 0; k < 8; ++k) em[k] = w[(l + 64 * k) * 32 + (tcur[k] - 1)];
        float acc = 0.0f;
        #pragma unroll
        for (int k = 0; k < 8; ++k) {
            int t  = l + 64 * k;
            int nx = tg[(t + 1) & 511];
            nx = (t == 511) ? 33 : nx;            // end term trans[tag_511][STOP]
            acc += em[k] + tlds[tcur[k] * 34 + nx];
        }
        if (l == 0) acc += tlds[tg[0]];           // start term trans[0][tag_0]
        acc += __shfl_xor(acc, 1);
        acc += __shfl_xor(acc, 2);
        acc += __shfl_xor(acc, 4);
        acc += __shfl_xor(acc, 8);
        acc += __shfl_xor(acc, 16);
        acc += __shfl_xor(acc, 32);
        if (bb == 0) ps0 = acc; else ps1 = acc;
    }
    float ps = (bp == 0) ? ps0 : ps1;
    if ((l & 31) == 0) out[bbase + bp] = total - ps;  // lanes 0 and 32 write
}

extern "C" void kernel_launch(void* const* d_in, const int* in_sizes, int n_in,
                              void* d_out, int out_size, void* d_ws, size_t ws_size,
                              hipStream_t stream) {
    const float* wtv   = (const float*)d_in[0];
    const float* trans = (const float*)d_in[1];
    const int*   rtag  = (const int*)d_in[2];
    (void)in_sizes; (void)n_in; (void)d_ws; (void)ws_size; (void)out_size;
    float* out = (float*)d_out;
    crf_kernel<<<256, 64, 0, stream>>>(wtv, trans, rtag, out);
}

// Round 10
// 120.861 us; speedup vs baseline: 1.2145x; 1.2145x over previous
//
#include <hip/hip_runtime.h>

// CRF loss on MI355X — half-split dot products, staggered 2-phase, 1 batch/wave.
// B=512, L=512, T=32, S=34. Output f32[512]. 512 blocks x 64 threads.
//
// Ring model (R7/R8/R9 evidence): per direction, step latency = publish ->
// read-FIFO drain -> FMA tail -> publish. The 8-read drain (~120+7*12 cy)
// dominates. Fix: lane (s,h) = (l&31, l>>5) accumulates only input half
// p in [16h,16h+16) -> 4 ds_read_b128 per exchange; halves combine with one
// v_permlane32_swap_b32 (VALU, ~8cy; NOT shfl_xor(32) which is a DS
// round-trip). Both halves then hold bit-identical full sums (fp add is
// commutative), so rescale exponents stay uniform per chain.
// R7's permlane bug avoided structurally: swap operands are distinct SSA
// defs (one via opaque v_mov), both live -> RA cannot coalesce them.
// Staggered slots as R8 (verified): slot O = bwd exchange | fwd FMA,
// slot E = fwd exchange | bwd FMA. Emission ring + BIAS/rescale-16 +
// gold-path epilogue carried over unchanged.

typedef float f32x2 __attribute__((ext_vector_type(2)));

#define F2   1.4426950408889634f   // log2(e)
#define LN2  0.6931471805599453f
#define BIAS 0.0078125f            // 2^-7, exact
#define BIASCNT 3577               // 7 * 511 applications of biased tc

__device__ __forceinline__ float grpmax32(float x) {
    // max over each 32-lane group: 4 DPP row_ror fmax + ds_swizzle xor-16.
    // (verified absmax 0.0 in rounds 4-6, 8)
    int t;
    t = __builtin_amdgcn_update_dpp(__float_as_int(x), __float_as_int(x), 0x121, 0xf, 0xf, true);
    x = fmaxf(x, __int_as_float(t));   // row_ror:1
    t = __builtin_amdgcn_update_dpp(__float_as_int(x), __float_as_int(x), 0x122, 0xf, 0xf, true);
    x = fmaxf(x, __int_as_float(t));   // row_ror:2
    t = __builtin_amdgcn_update_dpp(__float_as_int(x), __float_as_int(x), 0x124, 0xf, 0xf, true);
    x = fmaxf(x, __int_as_float(t));   // row_ror:4
    t = __builtin_amdgcn_update_dpp(__float_as_int(x), __float_as_int(x), 0x128, 0xf, 0xf, true);
    x = fmaxf(x, __int_as_float(t));   // row_ror:8 -> per-16 max
    t = __builtin_amdgcn_ds_swizzle(__float_as_int(x), 0x401F);  // xor 16
    x = fmaxf(x, __int_as_float(t));
    return x;
}

__device__ __forceinline__ float xhalf_sum(float v) {
    // sum of v over lane pairs (l, l^32) via v_permlane32_swap_b32 (VALU).
    // b is a distinct SSA def (opaque mov) so RA gives a,b distinct regs.
    int a = __float_as_int(v);
    int b;
    asm("v_mov_b32 %0, %1" : "=v"(b) : "v"(a));
    asm("v_permlane32_swap_b32 %0, %1" : "+v"(a), "+v"(b));
    // newA[l] = v[l<32 ? l : l-32], newB[l] = v[l<32 ? l+32 : l]
    return __int_as_float(a) + __int_as_float(b);   // = v[l] + v[l^32]
}

__global__ __launch_bounds__(64, 1) void crf_kernel(
    const float* __restrict__ wtv,    // [512,512,32]
    const float* __restrict__ trans,  // [34,34]
    const int*   __restrict__ rtag,   // [512,512]
    float* __restrict__ out)          // [512]
{
    __shared__ __align__(16) float tlds[1156];  // raw translation (ln domain)
    __shared__ __align__(16) int   ltag[512];   // gold tags, 1 batch
    __shared__ __align__(16) float alds[144];   // wF: [0..63], wB: [80..143]

    const int l = threadIdx.x;
    const int s = l & 31;        // state-1 (this lane's output state)
    const int h = l >> 5;        // input half: p in [16h, 16h+16)
    const int b = blockIdx.x;

    for (int k = l; k < 1156; k += 64) tlds[k] = trans[k];
    {
        const int* rtb = rtag + (size_t)b * 512;
        for (int k = l; k < 512; k += 64) ltag[k] = rtb[k];
    }
    __syncthreads();  // once, before the main loop (graph-safe)

    // exp2-domain transitions (biased) for this lane's 16 input p's, packed:
    // read k (k=0..3) returns alphas p = 16h+4k .. +3; pair {p,p+1} / {p+2,p+3}.
    f32x2 tcF2[8], tcB2[8];
    #pragma unroll
    for (int k = 0; k < 4; ++k) {
        const int p0 = 16 * h + 4 * k;
        f32x2 vA, vB, wA, wB2;
        vA.x = __builtin_exp2f(F2 * tlds[(p0 + 1) * 34 + (s + 1)]) * BIAS;
        vA.y = __builtin_exp2f(F2 * tlds[(p0 + 2) * 34 + (s + 1)]) * BIAS;
        vB.x = __builtin_exp2f(F2 * tlds[(p0 + 3) * 34 + (s + 1)]) * BIAS;
        vB.y = __builtin_exp2f(F2 * tlds[(p0 + 4) * 34 + (s + 1)]) * BIAS;
        wA.x = __builtin_exp2f(F2 * tlds[(s + 1) * 34 + (p0 + 1)]) * BIAS;
        wA.y = __builtin_exp2f(F2 * tlds[(s + 1) * 34 + (p0 + 2)]) * BIAS;
        wB2.x = __builtin_exp2f(F2 * tlds[(s + 1) * 34 + (p0 + 3)]) * BIAS;
        wB2.y = __builtin_exp2f(F2 * tlds[(s + 1) * 34 + (p0 + 4)]) * BIAS;
        tcF2[2 * k] = vA; tcF2[2 * k + 1] = vB;
        tcB2[2 * k] = wA; tcB2[2 * k + 1] = wB2;
    }
    // START term (fwd, step 1): added in half 0's partial only
    float ai = (h == 0) ? __builtin_exp2f(F2 * tlds[s + 1]) * BIAS : 0.0f;

    const float* wbq = wtv + (size_t)b * (512 * 32);
    const float* wl  = wbq + s;

    float stF = __builtin_exp2f(F2 * wl[0]);    // alpha_0 (replicated both halves)
    float stB = 1.0f;                           // b_511
    int scF = 0, scB = 0;

    // emission ring (8 ahead): step i uses row i (fwd) / 512-i (bwd)
    float vnF[16], vnB[16];
    #pragma unroll
    for (int j = 0; j < 8; ++j) {
        vnF[j] = wl[(1 + j) * 32];             // rows 1..8
        vnB[j] = wl[(511 - j) * 32];           // rows 511..504
    }
    float eoF_c = __builtin_exp2f(F2 * vnF[0]);   // emission factor, step 1
    float gB    = __builtin_exp2f(F2 * vnB[0]);   // g_1 = b_511 * eo(row 511)

    float* wF = alds;                  // fwd publish region (64 floats)
    float* wB = alds + 80;             // bwd publish region (64 floats)
    const float4* rf4 = (const float4*)(alds + 16 * h);        // alphas p=16h..16h+15
    const float4* rb4 = (const float4*)(alds + 80 + 16 * h);   // g's    p=16h..16h+15

    float4 ra[4], rb[4];

    // ---- prologue: publish alpha_0, issue fwd reads ----
    wF[l] = stF;
    __builtin_amdgcn_wave_barrier();
    #pragma unroll
    for (int k = 0; k < 4; ++k) ra[k] = rf4[k];
    __builtin_amdgcn_wave_barrier();

    for (int t0 = 1; t0 <= 241; t0 += 16) {   // 16 bodies x 16 steps = i = 1..256
        #pragma unroll
        for (int j = 0; j < 16; ++j) {
            const int i = t0 + j;

            // ---- SLOT O: publish bwd g_i, issue bwd reads | shadow |
            //      fwd half-FMA + cross-half combine, step i ----
            wB[l] = gB;
            __builtin_amdgcn_wave_barrier();
            #pragma unroll
            for (int k = 0; k < 4; ++k) rb[k] = rb4[k];
            __builtin_amdgcn_wave_barrier();
            // shadow: bwd emission prefetch (tail rows >= 248: in-bounds) +
            // next-step bwd emission factor
            vnB[(j + 8) & 15] = wl[(512 - (i + 8)) * 32];
            float eoB_n = __builtin_exp2f(F2 * vnB[(j + 1) & 15]);
            {
                f32x2 a01 = {ai, 0.0f};
                f32x2 a23 = {0.0f, 0.0f};
                ai = 0.0f;
                #pragma unroll
                for (int k = 0; k < 4; ++k) {
                    float4 x = ra[k];
                    f32x2 xlo = {x.x, x.y};
                    f32x2 xhi = {x.z, x.w};
                    a01 = __builtin_elementwise_fma(xlo, tcF2[2 * k + 0], a01);
                    a23 = __builtin_elementwise_fma(xhi, tcF2[2 * k + 1], a23);
                }
                float part = (a01.x + a01.y) + (a23.x + a23.y);
                float sum  = xhalf_sum(part);            // full 32-input dot
                stF = sum * eoF_c;                       // fwd updates all i
            }
            if (j == 15) {
                // fwd rescale (every 16 steps) between update and publish
                float m = grpmax32(stF);
                int e = ((__float_as_int(m) >> 23) & 0xff) - 127;
                stF *= __int_as_float((127 - e) << 23);
                scF += e;
            }

            // ---- SLOT E: publish fwd alpha_i, issue fwd reads | shadow |
            //      bwd half-FMA + combine, step i ----
            wF[l] = stF;
            __builtin_amdgcn_wave_barrier();
            #pragma unroll
            for (int k = 0; k < 4; ++k) ra[k] = rf4[k];
            __builtin_amdgcn_wave_barrier();
            // shadow: fwd emission prefetch (tail rows <= 264: in-bounds) +
            // next-step fwd emission factor
            vnF[(j + 8) & 15] = wl[(i + 8) * 32];
            float eoF_n = __builtin_exp2f(F2 * vnF[(j + 1) & 15]);
            {
                f32x2 a01 = {0.0f, 0.0f};
                f32x2 a23 = {0.0f, 0.0f};
                #pragma unroll
                for (int k = 0; k < 4; ++k) {
                    float4 x = rb[k];
                    f32x2 xlo = {x.x, x.y};
                    f32x2 xhi = {x.z, x.w};
                    a01 = __builtin_elementwise_fma(xlo, tcB2[2 * k + 0], a01);
                    a23 = __builtin_elementwise_fma(xhi, tcB2[2 * k + 1], a23);
                }
                float part = (a01.x + a01.y) + (a23.x + a23.y);
                float sum  = xhalf_sum(part);
                stB = (i != 256) ? sum : stB;            // i==256: fwd-only tail
            }
            if (j == 15) {
                // bwd rescale at body end (before next publish)
                float m = grpmax32(stB);
                int e = ((__float_as_int(m) >> 23) & 0xff) - 127;
                stB *= __int_as_float((127 - e) << 23);
                scB += e;
            }
            gB    = stB * eoB_n;   // publish value for step i+1 (off write path)
            eoF_c = eoF_n;
        }
    }

    // ---- Z = sum_s af_256[s] * b_256[s] (sum within the 32-group; both
    //      halves hold identical replicas) ----
    float prod = stF * stB;
    prod += __shfl_xor(prod, 1);
    prod += __shfl_xor(prod, 2);
    prod += __shfl_xor(prod, 4);
    prod += __shfl_xor(prod, 8);
    prod += __shfl_xor(prod, 16);
    float total = ((float)(scF + scB + BIASCNT) + __builtin_log2f(prod)) * LN2;

    // ---- gold-path score epilogue (verified R3-R9), 1 batch ----
    const int* tg = ltag;
    int   tcur[8];
    float em[8];
    #pragma unroll
    for (int k = 0; k < 8; ++k) tcur[k] = tg[l + 64 * k];
    #pragma unroll
    for (int k = 0; k < 8; ++k) em[k] = wbq[(l + 64 * k) * 32 + (tcur[k] - 1)];
    float acc = 0.0f;
    #pragma unroll
    for (int k = 0; k < 8; ++k) {
        int t  = l + 64 * k;
        int nx = tg[(t + 1) & 511];
        nx = (t == 511) ? 33 : nx;            // end term trans[tag_511][STOP]
        acc += em[k] + tlds[tcur[k] * 34 + nx];
    }
    if (l == 0) acc += tlds[tg[0]];           // start term trans[0][tag_0]
    acc += __shfl_xor(acc, 1);
    acc += __shfl_xor(acc, 2);
    acc += __shfl_xor(acc, 4);
    acc += __shfl_xor(acc, 8);
    acc += __shfl_xor(acc, 16);
    acc += __shfl_xor(acc, 32);

    if (l == 0) out[b] = total - acc;
}

extern "C" void kernel_launch(void* const* d_in, const int* in_sizes, int n_in,
                              void* d_out, int out_size, void* d_ws, size_t ws_size,
                              hipStream_t stream) {
    const float* wtv   = (const float*)d_in[0];
    const float* trans = (const float*)d_in[1];
    const int*   rtag  = (const int*)d_in[2];
    (void)in_sizes; (void)n_in; (void)d_ws; (void)ws_size; (void)out_size;
    float* out = (float*)d_out;
    crf_kernel<<<512, 64, 0, stream>>>(wtv, trans, rtag, out);
}